// Round 3
// baseline (1211.096 us; speedup 1.0000x reference)
//
#include <hip/hip_runtime.h>
#include <math.h>

#define HID    1024
#define GG     64
#define KPROP  5
#define H1     512
#define H2     256
#define NCLS   40
#define BNEPS  1e-5f
#define TILE   2048
#define BPART  256     // partition blocks
#define NBINS  1024    // buckets of 128 nodes (supports n <= 131072)
#define LDSCAP 8192    // max edges per bucket staged in LDS (mean ~4096, sd ~64)
#define TS     8192    // source-tile size for LDS-staged gather (128KB of float4)
#define TSH    13      // log2(TS)
#define MAXB   4       // max buckets per gather block (nbuck<=1024, 256 blocks)
#define TPS    20      // tptr stride per bucket (>= max ntiles+1 = 17)

__host__ __device__ static inline int cdiv(int a, int b) { return (a + b - 1) / b; }

// ---------- Pass A: per-block histogram of col>>7 ----------
__global__ __launch_bounds__(1024) void k_hista(const int* __restrict__ col,
                                                int* __restrict__ blockHist, int e) {
    __shared__ int h[NBINS];
    for (int i = threadIdx.x; i < NBINS; i += 1024) h[i] = 0;
    __syncthreads();
    int chunk = cdiv(e, gridDim.x);
    int s = blockIdx.x * chunk, t = min(e, s + chunk);
    for (int i = s + threadIdx.x; i < t; i += 1024) atomicAdd(&h[col[i] >> 7], 1);
    __syncthreads();
    for (int i = threadIdx.x; i < NBINS; i += 1024)
        blockHist[blockIdx.x * NBINS + i] = h[i];
}

// ---------- Pass B: per-(block,bucket) exclusive offsets + bucket starts ----------
__global__ __launch_bounds__(1024) void k_scan(const int* __restrict__ blockHist,
                                               int* __restrict__ blockOff,
                                               int* __restrict__ bucketStart, int e) {
    __shared__ int tot[NBINS];
    int bin = threadIdx.x;
    int s = 0;
    for (int b = 0; b < BPART; b++) {
        int v = blockHist[b * NBINS + bin];
        blockOff[b * NBINS + bin] = s;   // coalesced (bin contiguous across threads)
        s += v;
    }
    tot[bin] = s;
    __syncthreads();
    if (bin == 0) {
        int acc = 0;
        for (int i = 0; i < NBINS; i++) { int v = tot[i]; tot[i] = acc; acc += v; }
    }
    __syncthreads();
    bucketStart[bin] = tot[bin];
    if (bin == 0) bucketStart[NBINS] = e;
}

// ---------- Pass C: scatter edges into bucket-sorted order (packed) ----------
__global__ __launch_bounds__(1024) void k_scat(const int* __restrict__ row,
                                               const int* __restrict__ col,
                                               const int* __restrict__ blockOff,
                                               const int* __restrict__ bucketStart,
                                               int* __restrict__ ebuf, int e) {
    __shared__ int c2[NBINS];
    for (int i = threadIdx.x; i < NBINS; i += 1024) c2[i] = 0;
    __syncthreads();
    int chunk = cdiv(e, gridDim.x);
    int s = blockIdx.x * chunk, t = min(e, s + chunk);
    const int* boff = blockOff + blockIdx.x * NBINS;
    for (int i = s + threadIdx.x; i < t; i += 1024) {
        int c = col[i];
        int bin = c >> 7;
        int lr = atomicAdd(&c2[bin], 1);                 // LDS atomic — cheap
        int pos = bucketStart[bin] + boff[bin] + lr;     // globally unique
        ebuf[pos] = row[i] | ((c & 127) << 17);          // src<2^17, 7-bit local target
    }
}

// ---------- Pass D: per-bucket sort edges by SOURCE-TILE + deg + fused z0 init ----------
// (was: compact per-target CSR; the tiled gather needs (bucket,tile) segments, and
// per-target order is no longer required since accumulation goes through LDS slots)
__global__ __launch_bounds__(256) void k_csr(const int* __restrict__ bucketStart,
                                             int* __restrict__ ebuf,
                                             int* __restrict__ tptr, int* __restrict__ deg,
                                             const float* __restrict__ pos,
                                             float4* __restrict__ z0, int n, int ntiles) {
    __shared__ int eb[LDSCAP];
    __shared__ int cnt[128];
    __shared__ int tc[17];
    __shared__ int tp[17];
    int g = blockIdx.x;
    int s0 = bucketStart[g], s1 = bucketStart[g + 1];
    int m = s1 - s0; if (m > LDSCAP) m = LDSCAP;
    for (int i = threadIdx.x; i < m; i += 256) eb[i] = ebuf[s0 + i];
    if (threadIdx.x < 128) cnt[threadIdx.x] = 0;
    if (threadIdx.x < 17) tc[threadIdx.x] = 0;
    __syncthreads();
    for (int i = threadIdx.x; i < m; i += 256) {
        int v = eb[i];
        atomicAdd(&cnt[(v >> 17) & 127], 1);          // per-target count -> deg
        atomicAdd(&tc[(v & 0x1FFFF) >> TSH], 1);      // per-source-tile count
    }
    __syncthreads();
    if (threadIdx.x == 0) {
        int acc = 0;
        for (int i = 0; i < ntiles; i++) { tp[i] = acc; acc += tc[i]; }
        tp[ntiles] = acc;
    }
    __syncthreads();
    if (threadIdx.x <= ntiles) tptr[g * TPS + threadIdx.x] = s0 + tp[threadIdx.x];
    int node = g * 128 + threadIdx.x;
    if (threadIdx.x < 128 && node < n) {
        int d = cnt[threadIdx.x];
        deg[node] = d;
        float dis = rsqrtf((float)(d + 1));
        z0[node] = make_float4(dis * pos[3 * node], dis * pos[3 * node + 1],
                               dis * pos[3 * node + 2], 0.f);
    }
    if (threadIdx.x < 17) tc[threadIdx.x] = 0;
    __syncthreads();
    for (int i = threadIdx.x; i < m; i += 256) {
        int v = eb[i];
        int t = (v & 0x1FFFF) >> TSH;
        int slot = tp[t] + atomicAdd(&tc[t], 1);
        ebuf[s0 + slot] = v;                          // keep (tgt|src) packing
    }
}

// ---------- tiled gather: random access -> LDS ----------
// R2 post-mortem: the gather is capped at ~7.8 scattered line-requests/cycle
// chip-wide (per-CU outstanding-miss cap x post-L2 latency; L2 can't stay warm
// across passes because cross-XCD visibility flushes it at kernel boundaries).
// ILP-16 vs ILP-8 changed nothing; more waves made it worse. Fix = remove the
// scattered requests entirely: stage zin in 128KB source-tiles in LDS (coalesced
// global streams only), accumulate per-target sums in LDS via ds_add_f32.
// 256 blocks (1/CU, LDS-bound), each owns 3-4 target-buckets.
template <bool FINAL>
__global__ __launch_bounds__(256) void k_gt(
    const int* __restrict__ ebuf, const int* __restrict__ tptr,
    const int* __restrict__ deg, const float4* __restrict__ zin,
    float4* __restrict__ zout, double* __restrict__ stats,
    int n, int nbuck, int nblk, int ntiles) {
    __shared__ float4 zt[TS];                 // 128 KB tile of zin
    __shared__ float acc[MAXB * 384];         // per-bucket {x[128],y[128],z[128]}
    long long bx = blockIdx.x;
    int b0 = (int)(bx * nbuck / nblk);
    int b1 = (int)((bx + 1) * nbuck / nblk);
    int nb = b1 - b0;
    for (int i = threadIdx.x; i < nb * 384; i += 256) acc[i] = 0.f;
    for (int t = 0; t < ntiles; t++) {
        int base = t << TSH;
        int cnt = min(TS, n - base);
        for (int i = threadIdx.x; i < cnt; i += 256) zt[i] = zin[base + i];
        __syncthreads();                      // also covers acc zeroing on t=0
        for (int bi = 0; bi < nb; bi++) {
            int g = b0 + bi;
            int es = tptr[g * TPS + t];
            int ee = tptr[g * TPS + t + 1];
            float* ab = acc + bi * 384;
            for (int idx = es + threadIdx.x; idx < ee; idx += 256) {
                int v = ebuf[idx];
                int tgt = (v >> 17) & 127;
                float4 z = zt[(v & 0x1FFFF) - base];
                atomicAdd(&ab[tgt], z.x);
                atomicAdd(&ab[128 + tgt], z.y);
                atomicAdd(&ab[256 + tgt], z.z);
            }
        }
        __syncthreads();
    }
    double v[9];
#pragma unroll
    for (int jj = 0; jj < 9; jj++) v[jj] = 0.0;
    if (threadIdx.x < 128) {
        for (int bi = 0; bi < nb; bi++) {
            int node = (b0 + bi) * 128 + threadIdx.x;
            if (node < n) {
                float4 zi = zin[node];        // self loop
                float* ab = acc + bi * 384;
                float s0 = ab[threadIdx.x] + zi.x;
                float s1 = ab[128 + threadIdx.x] + zi.y;
                float s2 = ab[256 + threadIdx.x] + zi.z;
                float dg = (float)(deg[node] + 1);
                float sc = FINAL ? rsqrtf(dg) : (1.f / dg);
                float x0 = sc * s0, x1 = sc * s1, x2 = sc * s2;
                zout[node] = make_float4(x0, x1, x2, 0.f);
                if (FINAL) {
                    v[0] += x0; v[1] += x1; v[2] += x2;
                    v[3] += (double)x0 * x0; v[4] += (double)x0 * x1;
                    v[5] += (double)x0 * x2; v[6] += (double)x1 * x1;
                    v[7] += (double)x1 * x2; v[8] += (double)x2 * x2;
                }
            }
        }
    }
    if (FINAL) {
#pragma unroll
        for (int jj = 0; jj < 9; jj++) {
            double tt = v[jj];
            for (int m = 1; m < 64; m <<= 1) tt += __shfl_xor(tt, m, 64);
            if ((threadIdx.x & 63) == 0) atomicAdd(&stats[jj], tt);
        }
    }
}

// ---------- graph boundaries via binary search (batch is sorted) ----------
__global__ void k_bounds(const int* __restrict__ batch, int* starts, int n) {
    int g = threadIdx.x;
    if (g <= GG) {
        int lo = 0, hi = n;
        while (lo < hi) {
            int mid = (lo + hi) >> 1;
            if (batch[mid] < g) lo = mid + 1; else hi = mid;
        }
        starts[g] = lo;
    }
}

// ---------- pooling: per (graph, channel) max/min of dot(x, W_c), fused BN0+ReLU ----------
__global__ __launch_bounds__(256) void k_pool(
    const float4* __restrict__ z, const int* __restrict__ starts,
    const float* __restrict__ lin_w,
    const float* __restrict__ bn0_g, const float* __restrict__ bn0_b,
    const double* __restrict__ stats, float* pooled, int n) {
    __shared__ float4 sh[TILE];
    int g = blockIdx.x;
    int c = blockIdx.y * 256 + threadIdx.x;

    float w0 = lin_w[c], w1 = lin_w[HID + c], w2 = lin_w[2 * HID + c];

    double invN = 1.0 / (double)n;
    double mu0 = stats[0] * invN, mu1 = stats[1] * invN, mu2 = stats[2] * invN;
    float c00 = (float)(stats[3] * invN - mu0 * mu0);
    float c01 = (float)(stats[4] * invN - mu0 * mu1);
    float c02 = (float)(stats[5] * invN - mu0 * mu2);
    float c11 = (float)(stats[6] * invN - mu1 * mu1);
    float c12 = (float)(stats[7] * invN - mu1 * mu2);
    float c22 = (float)(stats[8] * invN - mu2 * mu2);
    float meanc = (float)mu0 * w0 + (float)mu1 * w1 + (float)mu2 * w2;  // lin_b cancels in BN
    float var = c00 * w0 * w0 + c11 * w1 * w1 + c22 * w2 * w2
              + 2.f * (c01 * w0 * w1 + c02 * w0 * w2 + c12 * w1 * w2);
    var = fmaxf(var, 0.f);

    int s0 = starts[g], s1 = starts[g + 1];
    float mx = -INFINITY, mn = INFINITY;
    for (int base = s0; base < s1; base += TILE) {
        int cnt = min(TILE, s1 - base);
        __syncthreads();
        for (int j = threadIdx.x; j < cnt; j += 256) sh[j] = z[base + j];
        __syncthreads();
        for (int j = 0; j < cnt; j++) {
            float4 p = sh[j];
            float d = fmaf(p.x, w0, fmaf(p.y, w1, p.z * w2));
            mx = fmaxf(mx, d);
            mn = fminf(mn, d);
        }
    }
    float inv = rsqrtf(var + BNEPS);
    float s = bn0_g[c] * inv;
    float raw = (s >= 0.f) ? mx : mn;     // BN scale sign decides which extreme survives relu∘max
    float y = (raw - meanc) * s + bn0_b[c];
    pooled[g * HID + c] = fmaxf(y, 0.f);
}

// ---------- fused Linear + BN(over 64 rows = 1 wave) + ReLU; 1 wave per output column ----------
template <int KIN>
__global__ __launch_bounds__(64) void k_fcbn(
    const float* __restrict__ in, const float* __restrict__ W,
    const float* __restrict__ bias, const float* __restrict__ gamma,
    const float* __restrict__ beta, float* out, int Cout) {
    int c = blockIdx.x;
    int r = threadIdx.x;  // 64 rows == wave size
    const float* rowp = in + r * KIN;
    float acc = 0.f;
#pragma unroll 8
    for (int k = 0; k < KIN; k++) acc = fmaf(rowp[k], W[k * Cout + c], acc);
    float y = acc + bias[c];
    float sum = y, sq = y * y;
    for (int m = 1; m < 64; m <<= 1) {
        sum += __shfl_xor(sum, m, 64);
        sq  += __shfl_xor(sq, m, 64);
    }
    float mean = sum * (1.f / 64.f);
    float var  = fmaxf(sq * (1.f / 64.f) - mean * mean, 0.f);
    float o = (y - mean) * rsqrtf(var + BNEPS) * gamma[c] + beta[c];
    out[r * Cout + c] = fmaxf(o, 0.f);
}

// ---------- fc3 + log_softmax; 1 wave per row ----------
__global__ __launch_bounds__(64) void k_out(
    const float* __restrict__ in, const float* __restrict__ W,
    const float* __restrict__ bias, float* out) {
    int r = blockIdx.x;
    int c = threadIdx.x;
    bool act = c < NCLS;
    float z = -INFINITY;
    if (act) {
        const float* rowp = in + r * H2;
        float acc = 0.f;
#pragma unroll 8
        for (int k = 0; k < H2; k++) acc = fmaf(rowp[k], W[k * NCLS + c], acc);
        z = acc + bias[c];
    }
    float mx = z;
    for (int m = 1; m < 64; m <<= 1) mx = fmaxf(mx, __shfl_xor(mx, m, 64));
    float ex = act ? expf(z - mx) : 0.f;
    float se = ex;
    for (int m = 1; m < 64; m <<= 1) se += __shfl_xor(se, m, 64);
    if (act) out[r * NCLS + c] = z - mx - logf(se);
}

extern "C" void kernel_launch(void* const* d_in, const int* in_sizes, int n_in,
                              void* d_out, int out_size, void* d_ws, size_t ws_size,
                              hipStream_t stream) {
    const float* pos   = (const float*)d_in[0];
    const int*   ei    = (const int*)d_in[1];   // [2,E]: rows at [0,E), cols at [E,2E)
    const int*   batch = (const int*)d_in[2];
    const float* lin_w = (const float*)d_in[3];
    // d_in[4] lin_b cancels in BN0 centering
    const float* bn0_g = (const float*)d_in[5];
    const float* bn0_b = (const float*)d_in[6];
    const float* fc1_w = (const float*)d_in[7];
    const float* fc1_b = (const float*)d_in[8];
    const float* bn1_g = (const float*)d_in[9];
    const float* bn1_b = (const float*)d_in[10];
    const float* fc2_w = (const float*)d_in[11];
    const float* fc2_b = (const float*)d_in[12];
    const float* bn2_g = (const float*)d_in[13];
    const float* bn2_b = (const float*)d_in[14];
    const float* fc3_w = (const float*)d_in[15];
    const float* fc3_b = (const float*)d_in[16];

    int n = in_sizes[0] / 3;
    int e = in_sizes[1] / 2;
    int nbuck = cdiv(n, 128);
    int ntiles = cdiv(n, TS);
    int nblk = min(256, nbuck);

    auto align256 = [](size_t x) { return (x + 255) & ~(size_t)255; };
    char* w = (char*)d_ws;
    int*    blockHist = (int*)w;    w += align256((size_t)BPART * NBINS * 4);
    int*    blockOff  = (int*)w;    w += align256((size_t)BPART * NBINS * 4);
    int*    bucketSt  = (int*)w;    w += align256((NBINS + 1) * 4);
    int*    tptr      = (int*)w;    w += align256((size_t)nbuck * TPS * 4);
    int*    deg       = (int*)w;    w += align256((size_t)n * 4);
    int*    ebuf      = (int*)w;    w += align256((size_t)e * 4);
    float4* za        = (float4*)w; w += align256((size_t)n * 16);
    float4* zb        = (float4*)w; w += align256((size_t)n * 16);
    double* stats     = (double*)w; w += align256(9 * sizeof(double));
    int*    starts    = (int*)w;    w += align256((GG + 1) * 4);
    float*  pooled    = (float*)w;  w += align256((size_t)GG * HID * 4);
    float*  h1        = (float*)w;  w += align256((size_t)GG * H1 * 4);
    float*  h2        = (float*)w;  w += align256((size_t)GG * H2 * 4);

    (void)hipMemsetAsync(stats, 0, 9 * sizeof(double), stream);

    const int* erow = ei;
    const int* ecol = ei + e;

    k_hista<<<BPART, 1024, 0, stream>>>(ecol, blockHist, e);
    k_scan <<<1, NBINS, 0, stream>>>(blockHist, blockOff, bucketSt, e);
    k_scat <<<BPART, 1024, 0, stream>>>(erow, ecol, blockOff, bucketSt, ebuf, e);
    k_csr  <<<nbuck, 256, 0, stream>>>(bucketSt, ebuf, tptr, deg, pos, za, n, ntiles);

    // K=5 passes, double-buffered: za->zb->za->zb->za->zb (final in zb)
    k_gt<false><<<nblk, 256, 0, stream>>>(ebuf, tptr, deg, za, zb, stats, n, nbuck, nblk, ntiles);
    k_gt<false><<<nblk, 256, 0, stream>>>(ebuf, tptr, deg, zb, za, stats, n, nbuck, nblk, ntiles);
    k_gt<false><<<nblk, 256, 0, stream>>>(ebuf, tptr, deg, za, zb, stats, n, nbuck, nblk, ntiles);
    k_gt<false><<<nblk, 256, 0, stream>>>(ebuf, tptr, deg, zb, za, stats, n, nbuck, nblk, ntiles);
    k_gt<true ><<<nblk, 256, 0, stream>>>(ebuf, tptr, deg, za, zb, stats, n, nbuck, nblk, ntiles);

    k_bounds<<<1, 128, 0, stream>>>(batch, starts, n);
    k_pool<<<dim3(GG, HID / 256), 256, 0, stream>>>(zb, starts, lin_w, bn0_g, bn0_b, stats, pooled, n);
    k_fcbn<HID><<<H1, 64, 0, stream>>>(pooled, fc1_w, fc1_b, bn1_g, bn1_b, h1, H1);
    k_fcbn<H1><<<H2, 64, 0, stream>>>(h1, fc2_w, fc2_b, bn2_g, bn2_b, h2, H2);
    k_out<<<GG, 64, 0, stream>>>(h2, fc3_w, fc3_b, (float*)d_out);
}

// Round 5
// 636.924 us; speedup vs baseline: 1.9015x; 1.9015x over previous
//
#include <hip/hip_runtime.h>
#include <math.h>

#define HID    1024
#define GG     64
#define KPROP  5
#define H1     512
#define H2     256
#define NCLS   40
#define BNEPS  1e-5f
#define TILE   2048
#define BPART  64      // partition blocks (was 256: k_scan's serial loop is BPART long)
#define NBINS  1024    // buckets of 128 nodes (supports n <= 131072)
#define LDSCAP 8192    // max edges per bucket staged in LDS (mean ~4096, sd ~64)
#define RADJ   6       // diag repeat: adj-stream only
#define RZCO   4       // diag repeat: adj + coalesced-z

__host__ __device__ static inline int cdiv(int a, int b) { return (a + b - 1) / b; }

// ---------- Pass A: per-block histogram of col>>7 ----------
__global__ __launch_bounds__(1024) void k_hista(const int* __restrict__ col,
                                                int* __restrict__ blockHist, int e) {
    __shared__ int h[NBINS];
    for (int i = threadIdx.x; i < NBINS; i += 1024) h[i] = 0;
    __syncthreads();
    int chunk = cdiv(e, gridDim.x);
    int s = blockIdx.x * chunk, t = min(e, s + chunk);
    for (int i = s + threadIdx.x; i < t; i += 1024) atomicAdd(&h[col[i] >> 7], 1);
    __syncthreads();
    for (int i = threadIdx.x; i < NBINS; i += 1024)
        blockHist[blockIdx.x * NBINS + i] = h[i];
}

// ---------- Pass B: per-(block,bucket) exclusive offsets + bucket starts ----------
__global__ __launch_bounds__(1024) void k_scan(const int* __restrict__ blockHist,
                                               int* __restrict__ blockOff,
                                               int* __restrict__ bucketStart,
                                               int* __restrict__ rowptr, int e, int n) {
    __shared__ int tot[NBINS];
    int bin = threadIdx.x;
    int s = 0;
    for (int b = 0; b < BPART; b++) {
        int v = blockHist[b * NBINS + bin];
        blockOff[b * NBINS + bin] = s;   // coalesced (bin contiguous across threads)
        s += v;
    }
    tot[bin] = s;
    __syncthreads();
    if (bin == 0) {
        int acc = 0;
        for (int i = 0; i < NBINS; i++) { int v = tot[i]; tot[i] = acc; acc += v; }
        rowptr[n] = e;
    }
    __syncthreads();
    bucketStart[bin] = tot[bin];
    if (bin == 0) bucketStart[NBINS] = e;
}

// ---------- Pass C: scatter edges into bucket-sorted order (packed) ----------
__global__ __launch_bounds__(1024) void k_scat(const int* __restrict__ row,
                                               const int* __restrict__ col,
                                               const int* __restrict__ blockOff,
                                               const int* __restrict__ bucketStart,
                                               int* __restrict__ ebuf, int e) {
    __shared__ int c2[NBINS];
    for (int i = threadIdx.x; i < NBINS; i += 1024) c2[i] = 0;
    __syncthreads();
    int chunk = cdiv(e, gridDim.x);
    int s = blockIdx.x * chunk, t = min(e, s + chunk);
    const int* boff = blockOff + blockIdx.x * NBINS;
    for (int i = s + threadIdx.x; i < t; i += 1024) {
        int c = col[i];
        int bin = c >> 7;
        int lr = atomicAdd(&c2[bin], 1);                 // LDS atomic — cheap
        int pos = bucketStart[bin] + boff[bin] + lr;     // globally unique
        ebuf[pos] = row[i] | ((c & 127) << 17);          // row<2^17, 7-bit local node
    }
}

// ---------- Pass D: per-bucket compact CSR (in place) + deg + fused z0 init ----------
__global__ __launch_bounds__(256) void k_csr(const int* __restrict__ bucketStart,
                                             int* __restrict__ ebuf,
                                             int* __restrict__ rowptr, int* __restrict__ deg,
                                             const float* __restrict__ pos,
                                             float4* __restrict__ z0, int n) {
    __shared__ int eb[LDSCAP];
    __shared__ int cnt[128];
    __shared__ int lptr[128];
    int g = blockIdx.x;
    int s0 = bucketStart[g], s1 = bucketStart[g + 1];
    int m = s1 - s0; if (m > LDSCAP) m = LDSCAP;
    for (int i = threadIdx.x; i < m; i += 256) eb[i] = ebuf[s0 + i];
    if (threadIdx.x < 128) cnt[threadIdx.x] = 0;
    __syncthreads();
    for (int i = threadIdx.x; i < m; i += 256) atomicAdd(&cnt[(eb[i] >> 17) & 127], 1);
    __syncthreads();
    if (threadIdx.x == 0) {
        int acc = 0;
        for (int i = 0; i < 128; i++) { lptr[i] = acc; acc += cnt[i]; }
    }
    __syncthreads();
    int node = g * 128 + threadIdx.x;
    if (threadIdx.x < 128 && node < n) {
        rowptr[node] = s0 + lptr[threadIdx.x];
        int d = cnt[threadIdx.x];
        deg[node] = d;
        float dis = rsqrtf((float)(d + 1));
        z0[node] = make_float4(dis * pos[3 * node], dis * pos[3 * node + 1],
                               dis * pos[3 * node + 2], 0.f);
    }
    if (threadIdx.x < 128) cnt[threadIdx.x] = 0;
    __syncthreads();
    for (int i = threadIdx.x; i < m; i += 256) {
        int v = eb[i];
        int t7 = (v >> 17) & 127;
        int slot = lptr[t7] + atomicAdd(&cnt[t7], 1);
        ebuf[s0 + slot] = v & 0x1FFFF;    // safe: whole range already staged in LDS
    }
}

// ========== DIAGNOSTIC 1: adj+rowptr streaming only, RADJ repeats ==========
// dur/RADJ = cost of the coalesced workspace stream component of one pass.
// r-dependent start offset defeats LICM of the loads across repeats.
__global__ __launch_bounds__(256) void kD_adj(const int* __restrict__ adj,
                                              const int* __restrict__ rowptr,
                                              float* __restrict__ out, int n) {
    int i = blockIdx.x * blockDim.x + threadIdx.x;
    if (i >= n) return;
    int s = rowptr[i], t = rowptr[i + 1];
    int acc = 0;
    for (int r = 0; r < RADJ; r++) {
        int j = s + (r & 3);
        for (; j + 8 <= t; j += 8) {
            int4 qa = *(const int4*)(adj + j);
            int4 qb = *(const int4*)(adj + j + 4);
            acc += qa.x + qa.y + qa.z + qa.w + qb.x + qb.y + qb.z + qb.w;
        }
        for (; j < t; j++) acc += adj[j];
    }
    out[i] = (float)(acc & 0xFFFF);
}

// ========== DIAGNOSTIC 2: adj stream + WAVE-COALESCED z gathers, RZCO repeats ==========
// Same load counts/structure as a real pass, but a wave's 64 lanes read 64
// consecutive z elements (16 lines/instr instead of 64). real - dur/RZCO
// isolates the pure address-randomness penalty.
__global__ __launch_bounds__(256) void kD_zco(const int* __restrict__ adj,
                                              const int* __restrict__ rowptr,
                                              const float4* __restrict__ zin,
                                              float* __restrict__ out,
                                              int n, unsigned msk) {
    int i = blockIdx.x * blockDim.x + threadIdx.x;
    if (i >= n) return;
    int s = rowptr[i], t = rowptr[i + 1];
    unsigned lane = threadIdx.x & 63;
    unsigned wb = ((blockIdx.x * 4u + (threadIdx.x >> 6)) * 2654435761u) & msk;
    float s0 = 0.f, s1 = 0.f, s2 = 0.f;
    int ai = 0;
    for (int r = 0; r < RZCO; r++) {
        int j = s;
        for (; j + 8 <= t; j += 8) {
            int4 qa = *(const int4*)(adj + j);
            int4 qb = *(const int4*)(adj + j + 4);
            ai += qa.x + qa.y + qa.z + qa.w + qb.x + qb.y + qb.z + qb.w;
            unsigned b = wb + (unsigned)(j - s) * 64u + (unsigned)r * 7777u;
            float4 a0 = zin[(b        + lane) & msk], a1 = zin[(b + 64u  + lane) & msk];
            float4 a2 = zin[(b + 128u + lane) & msk], a3 = zin[(b + 192u + lane) & msk];
            float4 a4 = zin[(b + 256u + lane) & msk], a5 = zin[(b + 320u + lane) & msk];
            float4 a6 = zin[(b + 384u + lane) & msk], a7 = zin[(b + 448u + lane) & msk];
            s0 += a0.x + a1.x + a2.x + a3.x + a4.x + a5.x + a6.x + a7.x;
            s1 += a0.y + a1.y + a2.y + a3.y + a4.y + a5.y + a6.y + a7.y;
            s2 += a0.z + a1.z + a2.z + a3.z + a4.z + a5.z + a6.z + a7.z;
        }
        for (; j < t; j++) {
            ai += adj[j];
            float4 a = zin[(wb + (unsigned)(j - s) * 64u + lane) & msk];
            s0 += a.x; s1 += a.y; s2 += a.z;
        }
    }
    out[i] = s0 + s1 + s2 + (float)(ai & 7) * 1e-6f;
}

// ---------- gather pass over compact CSR, thread-per-node, ILP-8 (R0 exact) ----------
// Best measured config: 563us total. R1 (4x waves) 3.7x worse; R2 (NT+ILP16)
// neutral-cold / slightly worse warm; R3 (LDS tiles) 1.5x worse. Keep as-is
// this round; diagnostics above decompose the 170us.
template <bool FINAL>
__global__ __launch_bounds__(256) void k_gather(
    const int* __restrict__ adj, const int* __restrict__ rowptr,
    const float4* __restrict__ zin, float4* __restrict__ zout,
    double* stats, int n) {
    int i = blockIdx.x * blockDim.x + threadIdx.x;
    float x0 = 0.f, x1 = 0.f, x2 = 0.f;
    if (i < n) {
        int s = rowptr[i], t = rowptr[i + 1];
        float4 zi = zin[i];
        float s0 = zi.x, s1 = zi.y, s2 = zi.z;   // self loop
        float t0 = 0.f, t1 = 0.f, t2 = 0.f;
        int j = s;
        for (; j + 8 <= t; j += 8) {             // ILP-8: 8 z-gathers in flight
            int4 qa = *(const int4*)(adj + j);
            int4 qb = *(const int4*)(adj + j + 4);
            float4 a = zin[qa.x], b = zin[qa.y], c = zin[qa.z], d = zin[qa.w];
            float4 p = zin[qb.x], q = zin[qb.y], r = zin[qb.z], u = zin[qb.w];
            s0 += a.x + b.x + c.x + d.x;
            s1 += a.y + b.y + c.y + d.y;
            s2 += a.z + b.z + c.z + d.z;
            t0 += p.x + q.x + r.x + u.x;
            t1 += p.y + q.y + r.y + u.y;
            t2 += p.z + q.z + r.z + u.z;
        }
        if (j + 4 <= t) {                        // ILP-4 tail
            int4 qa = *(const int4*)(adj + j);
            float4 a = zin[qa.x], b = zin[qa.y], c = zin[qa.z], d = zin[qa.w];
            s0 += a.x + b.x + c.x + d.x;
            s1 += a.y + b.y + c.y + d.y;
            s2 += a.z + b.z + c.z + d.z;
            j += 4;
        }
        for (; j < t; j++) {
            float4 a = zin[adj[j]];
            s0 += a.x; s1 += a.y; s2 += a.z;
        }
        s0 += t0; s1 += t1; s2 += t2;
        float dg = (float)(t - s + 1);
        float sc = FINAL ? rsqrtf(dg) : (1.0f / dg);
        x0 = sc * s0; x1 = sc * s1; x2 = sc * s2;
        zout[i] = make_float4(x0, x1, x2, 0.f);
    }
    if (FINAL) {
        double v[9];
        v[0] = x0; v[1] = x1; v[2] = x2;
        v[3] = (double)x0 * x0; v[4] = (double)x0 * x1; v[5] = (double)x0 * x2;
        v[6] = (double)x1 * x1; v[7] = (double)x1 * x2; v[8] = (double)x2 * x2;
#pragma unroll
        for (int jj = 0; jj < 9; jj++) {
            double t = v[jj];
            for (int m = 1; m < 64; m <<= 1) t += __shfl_xor(t, m, 64);
            if ((threadIdx.x & 63) == 0) atomicAdd(&stats[jj], t);
        }
    }
}

// ---------- graph boundaries via binary search (batch is sorted) ----------
__global__ void k_bounds(const int* __restrict__ batch, int* starts, int n) {
    int g = threadIdx.x;
    if (g <= GG) {
        int lo = 0, hi = n;
        while (lo < hi) {
            int mid = (lo + hi) >> 1;
            if (batch[mid] < g) lo = mid + 1; else hi = mid;
        }
        starts[g] = lo;
    }
}

// ---------- pooling: per (graph, channel) max/min of dot(x, W_c), fused BN0+ReLU ----------
__global__ __launch_bounds__(256) void k_pool(
    const float4* __restrict__ z, const int* __restrict__ starts,
    const float* __restrict__ lin_w,
    const float* __restrict__ bn0_g, const float* __restrict__ bn0_b,
    const double* __restrict__ stats, float* pooled, int n) {
    __shared__ float4 sh[TILE];
    int g = blockIdx.x;
    int c = blockIdx.y * 256 + threadIdx.x;

    float w0 = lin_w[c], w1 = lin_w[HID + c], w2 = lin_w[2 * HID + c];

    double invN = 1.0 / (double)n;
    double mu0 = stats[0] * invN, mu1 = stats[1] * invN, mu2 = stats[2] * invN;
    float c00 = (float)(stats[3] * invN - mu0 * mu0);
    float c01 = (float)(stats[4] * invN - mu0 * mu1);
    float c02 = (float)(stats[5] * invN - mu0 * mu2);
    float c11 = (float)(stats[6] * invN - mu1 * mu1);
    float c12 = (float)(stats[7] * invN - mu1 * mu2);
    float c22 = (float)(stats[8] * invN - mu2 * mu2);
    float meanc = (float)mu0 * w0 + (float)mu1 * w1 + (float)mu2 * w2;  // lin_b cancels in BN
    float var = c00 * w0 * w0 + c11 * w1 * w1 + c22 * w2 * w2
              + 2.f * (c01 * w0 * w1 + c02 * w0 * w2 + c12 * w1 * w2);
    var = fmaxf(var, 0.f);

    int s0 = starts[g], s1 = starts[g + 1];
    float mx = -INFINITY, mn = INFINITY;
    for (int base = s0; base < s1; base += TILE) {
        int cnt = min(TILE, s1 - base);
        __syncthreads();
        for (int j = threadIdx.x; j < cnt; j += 256) sh[j] = z[base + j];
        __syncthreads();
        for (int j = 0; j < cnt; j++) {
            float4 p = sh[j];
            float d = fmaf(p.x, w0, fmaf(p.y, w1, p.z * w2));
            mx = fmaxf(mx, d);
            mn = fminf(mn, d);
        }
    }
    float inv = rsqrtf(var + BNEPS);
    float s = bn0_g[c] * inv;
    float raw = (s >= 0.f) ? mx : mn;     // BN scale sign decides which extreme survives relu∘max
    float y = (raw - meanc) * s + bn0_b[c];
    pooled[g * HID + c] = fmaxf(y, 0.f);
}

// ---------- fused Linear + BN(over 64 rows = 1 wave) + ReLU; 1 wave per output column ----------
template <int KIN>
__global__ __launch_bounds__(64) void k_fcbn(
    const float* __restrict__ in, const float* __restrict__ W,
    const float* __restrict__ bias, const float* __restrict__ gamma,
    const float* __restrict__ beta, float* out, int Cout) {
    int c = blockIdx.x;
    int r = threadIdx.x;  // 64 rows == wave size
    const float* rowp = in + r * KIN;
    float acc = 0.f;
#pragma unroll 8
    for (int k = 0; k < KIN; k++) acc = fmaf(rowp[k], W[k * Cout + c], acc);
    float y = acc + bias[c];
    float sum = y, sq = y * y;
    for (int m = 1; m < 64; m <<= 1) {
        sum += __shfl_xor(sum, m, 64);
        sq  += __shfl_xor(sq, m, 64);
    }
    float mean = sum * (1.f / 64.f);
    float var  = fmaxf(sq * (1.f / 64.f) - mean * mean, 0.f);
    float o = (y - mean) * rsqrtf(var + BNEPS) * gamma[c] + beta[c];
    out[r * Cout + c] = fmaxf(o, 0.f);
}

// ---------- fc3 + log_softmax; 1 wave per row ----------
__global__ __launch_bounds__(64) void k_out(
    const float* __restrict__ in, const float* __restrict__ W,
    const float* __restrict__ bias, float* out) {
    int r = blockIdx.x;
    int c = threadIdx.x;
    bool act = c < NCLS;
    float z = -INFINITY;
    if (act) {
        const float* rowp = in + r * H2;
        float acc = 0.f;
#pragma unroll 8
        for (int k = 0; k < H2; k++) acc = fmaf(rowp[k], W[k * NCLS + c], acc);
        z = acc + bias[c];
    }
    float mx = z;
    for (int m = 1; m < 64; m <<= 1) mx = fmaxf(mx, __shfl_xor(mx, m, 64));
    float ex = act ? expf(z - mx) : 0.f;
    float se = ex;
    for (int m = 1; m < 64; m <<= 1) se += __shfl_xor(se, m, 64);
    if (act) out[r * NCLS + c] = z - mx - logf(se);
}

extern "C" void kernel_launch(void* const* d_in, const int* in_sizes, int n_in,
                              void* d_out, int out_size, void* d_ws, size_t ws_size,
                              hipStream_t stream) {
    const float* pos   = (const float*)d_in[0];
    const int*   ei    = (const int*)d_in[1];   // [2,E]: rows at [0,E), cols at [E,2E)
    const int*   batch = (const int*)d_in[2];
    const float* lin_w = (const float*)d_in[3];
    // d_in[4] lin_b cancels in BN0 centering
    const float* bn0_g = (const float*)d_in[5];
    const float* bn0_b = (const float*)d_in[6];
    const float* fc1_w = (const float*)d_in[7];
    const float* fc1_b = (const float*)d_in[8];
    const float* bn1_g = (const float*)d_in[9];
    const float* bn1_b = (const float*)d_in[10];
    const float* fc2_w = (const float*)d_in[11];
    const float* fc2_b = (const float*)d_in[12];
    const float* bn2_g = (const float*)d_in[13];
    const float* bn2_b = (const float*)d_in[14];
    const float* fc3_w = (const float*)d_in[15];
    const float* fc3_b = (const float*)d_in[16];

    int n = in_sizes[0] / 3;
    int e = in_sizes[1] / 2;
    int nbuck = cdiv(n, 128);

    auto align256 = [](size_t x) { return (x + 255) & ~(size_t)255; };
    char* w = (char*)d_ws;
    int*    blockHist = (int*)w;    w += align256((size_t)BPART * NBINS * 4);
    int*    blockOff  = (int*)w;    w += align256((size_t)BPART * NBINS * 4);
    int*    bucketSt  = (int*)w;    w += align256((NBINS + 1) * 4);
    int*    rowptr    = (int*)w;    w += align256((size_t)(n + 1) * 4);
    int*    deg       = (int*)w;    w += align256((size_t)n * 4);
    int*    ebuf      = (int*)w;    w += align256((size_t)e * 4);
    float4* za        = (float4*)w; w += align256((size_t)n * 16);
    float4* zb        = (float4*)w; w += align256((size_t)n * 16);
    double* stats     = (double*)w; w += align256(9 * sizeof(double));
    int*    starts    = (int*)w;    w += align256((GG + 1) * 4);
    float*  pooled    = (float*)w;  w += align256((size_t)GG * HID * 4);
    float*  h1        = (float*)w;  w += align256((size_t)GG * H1 * 4);
    float*  h2        = (float*)w;  w += align256((size_t)GG * H2 * 4);

    (void)hipMemsetAsync(stats, 0, 9 * sizeof(double), stream);

    const int* erow = ei;
    const int* ecol = ei + e;

    k_hista<<<BPART, 1024, 0, stream>>>(ecol, blockHist, e);
    k_scan <<<1, NBINS, 0, stream>>>(blockHist, blockOff, bucketSt, rowptr, e, n);
    k_scat <<<BPART, 1024, 0, stream>>>(erow, ecol, blockOff, bucketSt, ebuf, e);
    k_csr  <<<nbuck, 256, 0, stream>>>(bucketSt, ebuf, rowptr, deg, pos, za, n);

    int gn = cdiv(n, 256);

    // ----- diagnostics (read-only; write to dead blockHist region; absmax unaffected)
    {
        float* diag = (float*)blockHist;          // blockHist+blockOff dead after k_csr
        unsigned msk = 1;
        while ((msk << 1) <= (unsigned)n) msk <<= 1;
        msk -= 1;                                 // largest pow2 <= n, minus 1
        kD_adj<<<gn, 256, 0, stream>>>(ebuf, rowptr, diag, n);
        kD_zco<<<gn, 256, 0, stream>>>(ebuf, rowptr, za, diag, n, msk);
    }

    k_bounds<<<1, 128, 0, stream>>>(batch, starts, n);

    // K=5 passes, double-buffered: za->zb->za->zb->za->zb (final in zb)
    k_gather<false><<<gn, 256, 0, stream>>>(ebuf, rowptr, za, zb, stats, n);
    k_gather<false><<<gn, 256, 0, stream>>>(ebuf, rowptr, zb, za, stats, n);
    k_gather<false><<<gn, 256, 0, stream>>>(ebuf, rowptr, za, zb, stats, n);
    k_gather<false><<<gn, 256, 0, stream>>>(ebuf, rowptr, zb, za, stats, n);
    k_gather<true ><<<gn, 256, 0, stream>>>(ebuf, rowptr, za, zb, stats, n);

    k_pool<<<dim3(GG, HID / 256), 256, 0, stream>>>(zb, starts, lin_w, bn0_g, bn0_b, stats, pooled, n);
    k_fcbn<HID><<<H1, 64, 0, stream>>>(pooled, fc1_w, fc1_b, bn1_g, bn1_b, h1, H1);
    k_fcbn<H1><<<H2, 64, 0, stream>>>(h1, fc2_w, fc2_b, bn2_g, bn2_b, h2, H2);
    k_out<<<GG, 64, 0, stream>>>(h2, fc3_w, fc3_b, (float*)d_out);
}